// Round 15
// baseline (274.375 us; speedup 1.0000x reference)
//
#include <hip/hip_runtime.h>
#include <cstdint>
#include <cstddef>

// R20: R19 (single fused kernel, champion) with two scheduling changes:
//  1. __launch_bounds__(512, 1): LDS (142KB) already forces 1 block/CU, so
//     the old (512,2) 128-VGPR cap bought nothing -- VGPR_Count was pinned
//     at exactly 128. Freeing to ~256/wave gives the compiler slack for the
//     GEMM+epilogue interleave (2 waves/SIMD x 256 <= pool).
//  2. A-load ring deepened 4->8 slots (16 loads in flight at ramp), with the
//     P-prologue loads issued FIRST (deepest in queue) -- targets the
//     post-barrier ramp where A touches freshly-written L2 lines (~300cyc).
// Everything else (inline staging, P exchange, warming, wave-private phases,
// block-major layouts, 16-block ticket barrier) is R19 verbatim.

typedef __attribute__((ext_vector_type(8))) _Float16 f16x8;
typedef __attribute__((ext_vector_type(4))) float floatx4;

__device__ unsigned g_cnt[8 * 64];     // per-XCD registration tickets
__device__ unsigned g_gbar[16 * 64];   // per-group barrier counters (padded)

// g_h[t]: [16 grp][16 cgrp][256 rows][32 cols] fp16 (cgrp slab = 16KB).
// g_P[t]: [16 grp][16 cgrp][512] f32 (block slab = 2KB).
__device__ __align__(256) _Float16 g_h[12][16 * 16 * 256 * 32];
__device__ __align__(256) float    g_P[12][16 * 16 * 512];

__device__ __forceinline__ float sigm_f(float v) { return 1.0f / (1.0f + __expf(-v)); }
__device__ __forceinline__ float tanh_f(float v) { return 2.0f / (1.0f + __expf(-2.0f * v)) - 1.0f; }

__device__ __forceinline__ void async16(void* lds, const void* g) {
    __builtin_amdgcn_global_load_lds(
        (const __attribute__((address_space(1))) void*)g,
        (__attribute__((address_space(3))) void*)lds, 16, 0, 0);
}

// Load 8 cols of the virtual zx row i (cols 0..127 = z, 128..255 = x) as fp16.
__device__ __forceinline__ f16x8 ldzx8(const float* __restrict__ z,
                                       const float* __restrict__ x,
                                       int i, int c) {
    const float* s = (c < 128) ? (z + (size_t)i * 128 + c)
                               : (x + (size_t)i * 128 + (c - 128));
    float4 a = ((const float4*)s)[0], b = ((const float4*)s)[1];
    return (f16x8){(_Float16)a.x, (_Float16)a.y, (_Float16)a.z, (_Float16)a.w,
                   (_Float16)b.x, (_Float16)b.y, (_Float16)b.z, (_Float16)b.w};
}

// Per-group barrier: EXACTLY 16 co-resident same-XCD blocks (validated R11-R19).
__device__ __forceinline__ void group_barrier16(unsigned gidx) {
    asm volatile("s_waitcnt vmcnt(0)" ::: "memory");
    __syncthreads();
    if (threadIdx.x == 0) {
        unsigned* ctr = &g_gbar[gidx * 64];
        unsigned t = __hip_atomic_fetch_add(ctr, 1u, __ATOMIC_RELAXED,
                                            __HIP_MEMORY_SCOPE_AGENT);
        unsigned target = (t & ~15u) + 16u;
        while (__hip_atomic_load(ctr, __ATOMIC_RELAXED,
                                 __HIP_MEMORY_SCOPE_AGENT) < target)
            __builtin_amdgcn_s_sleep(1);
    }
    __syncthreads();
}

// ---------------- K: fully fused (prep + pre-GEMM + 12-step GRU) ----------------
// LDS: B @0 (96KB steady; 64KB pre-phase overlap), hstore[256][32]h @98304
// (16KB), xs[8][64]f @114688 (2KB), douts[8][12][64]f @116736 (24KB),
// dummy @141312 (1KB), slot @142336. Request 142400 (>80KB => 1 blk/CU).
__global__ __launch_bounds__(512, 1) void k_all(
    const float* __restrict__ z, const float* __restrict__ x,
    const float* __restrict__ x0, const float* __restrict__ W_ia,
    const float* __restrict__ b_ia, const float* __restrict__ W_h0,
    const float* __restrict__ b_h0, const float* __restrict__ W_ih,
    const float* __restrict__ b_ih, const float* __restrict__ W_hh,
    const float* __restrict__ b_hh, const float* __restrict__ W_out,
    const float* __restrict__ b_out, float* __restrict__ dout)
{
    extern __shared__ __align__(16) char smem[];
    const uint32_t BOFF = 0, HST = 98304, XSO = 114688, DOUT = 116736,
                   DUM = 141312, SLO = 142336;
    const int tid = threadIdx.x;
    float* xs = (float*)(smem + XSO);
    float* douts = (float*)(smem + DOUT);

    // ---- XCD discovery + registration (1 blk/CU => exactly 32 blks/XCD) ----
    unsigned xcc;
    asm volatile("s_getreg_b32 %0, hwreg(HW_REG_XCC_ID)" : "=s"(xcc));
    xcc &= 7u;
    if (tid == 0) {
        unsigned s = __hip_atomic_fetch_add(&g_cnt[xcc * 64], 1u, __ATOMIC_RELAXED,
                                            __HIP_MEMORY_SCOPE_AGENT) & 31u;
        *(unsigned*)(smem + SLO) = s;
    }
    __syncthreads();
    const unsigned slot = *(volatile unsigned*)(smem + SLO);
    const int shalf = slot >> 4, cgrp = slot & 15;
    const unsigned gidx = xcc * 2 + shalf;      // 0..15, 16 blocks each
    const int M0g = (int)gidx * 256;            // group's global sample base
    const int jc0 = cgrp * 32;                  // block's 32 h-cols (x3 gates)

    const int wv = tid >> 6, lane = tid & 63;
    const int l15 = lane & 15, q2 = lane >> 4;

    // ---- warm g_h[0] + g_P[0] own regions (one-time RFO prefetch) ----
    if (wv == 0) {
        const char* wb = (const char*)&g_h[0][0] + (size_t)gidx * 262144 +
                         (size_t)cgrp * 16384 + (size_t)lane * 128;
        async16(smem + DUM, wb);
        async16(smem + DUM, wb + 8192);
    }
    if (wv == 1) {
        const char* wp = (const char*)&g_P[0][0] +
                         ((size_t)gidx * 8192 + (size_t)cgrp * 512) * 4 +
                         (size_t)(lane & 15) * 128;
        async16(smem + DUM, wp);
    }

    // ---- inline pre-B staging: 128 rows x 256 fp16 (512B rows) from f32 ----
    #pragma unroll
    for (int u = 0; u < 8; u++) {
        int sl2 = u * 512 + tid;            // 0..4095
        int r = sl2 >> 5, s = sl2 & 31;     // row 0..127, slot 0..31
        int c = (s ^ (r & 15)) << 3;        // col base, multiple of 8
        f16x8 v;
        if (r < 96) {
            int nrow = (r >> 5) * 512 + jc0 + (r & 31);     // W_ih row
            const float2* src = (const float2*)(W_ih + (size_t)nrow * 258 + c);
            float2 a0 = src[0], a1 = src[1], a2 = src[2], a3 = src[3];
            v = (f16x8){(_Float16)a0.x, (_Float16)a0.y, (_Float16)a1.x, (_Float16)a1.y,
                        (_Float16)a2.x, (_Float16)a2.y, (_Float16)a3.x, (_Float16)a3.y};
        } else {
            int nrow = jc0 + (r - 96);                      // W_h0 row
            const float4* src = (const float4*)(W_h0 + (size_t)nrow * 256 + c);
            float4 a = src[0], b = src[1];
            v = (f16x8){(_Float16)a.x, (_Float16)a.y, (_Float16)a.z, (_Float16)a.w,
                        (_Float16)b.x, (_Float16)b.y, (_Float16)b.z, (_Float16)b.w};
        }
        *(f16x8*)(smem + (uint32_t)(r * 512 + s * 16)) = v;
    }

    // ---- t-invariant params: direct f32 scalar loads ----
    float4 p0v[2], p1v[2], p2v[2]; float wo0[2], wo1[2];
    float bih[3][2], bh0[2];
    #pragma unroll
    for (int jt = 0; jt < 2; jt++) {
        int jc = jc0 + jt * 16 + l15;
        p0v[jt] = make_float4(W_ih[(size_t)jc * 258 + 256],
                              W_ih[(size_t)jc * 258 + 257],
                              W_ih[(size_t)(512 + jc) * 258 + 256],
                              W_ih[(size_t)(512 + jc) * 258 + 257]);
        p1v[jt] = make_float4(W_ih[(size_t)(1024 + jc) * 258 + 256],
                              W_ih[(size_t)(1024 + jc) * 258 + 257],
                              b_hh[jc], b_hh[512 + jc]);
        p2v[jt] = make_float4(b_hh[1024 + jc], W_out[jc], W_out[512 + jc], 0.f);
        wo0[jt] = p2v[jt].y; wo1[jt] = p2v[jt].z;
        bh0[jt] = b_h0[jc];
        #pragma unroll
        for (int g = 0; g < 3; g++) bih[g][jt] = b_ih[g * 512 + jc];
    }
    const float bo = b_out[lane & 1];
    const float bia_d = b_ia[lane & 1];
    float4 wia_d = make_float4(W_ia[(lane & 1) * 4 + 0], W_ia[(lane & 1) * 4 + 1],
                               W_ia[(lane & 1) * 4 + 2], W_ia[(lane & 1) * 4 + 3]);

    uint32_t bbase[6];   // steady B (96 rows x 1024B) [validated swizzle]
    #pragma unroll
    for (int g = 0; g < 3; g++)
        #pragma unroll
        for (int jt = 0; jt < 2; jt++) {
            int r = g * 32 + jt * 16 + l15;
            bbase[g * 2 + jt] = BOFF + (uint32_t)r * 1024 +
                                ((uint32_t)(q2 ^ (r & 3)) << 4) +
                                ((uint32_t)((r >> 2) & 3) << 6);
        }
    uint32_t pb[8];      // pre-B (128 rows x 512B): 0..5 gates, 6..7 h0
    #pragma unroll
    for (int sl = 0; sl < 8; sl++) {
        int r = (sl < 6) ? ((sl >> 1) * 32 + (sl & 1) * 16 + l15)
                         : (96 + (sl - 6) * 16 + l15);
        pb[sl] = BOFF + (uint32_t)r * 512 +
                 ((uint32_t)(q2 ^ (r & 3)) << 4) +
                 ((uint32_t)((r >> 2) & 3) << 6);
    }
    __syncthreads();   // pre-B staged (ds_writes drained by barrier)

    // ---- pre-GEMM: K=256, A from z/x f32 (cvt in-register), 8 ks ----
    const int ia0 = M0g + (wv * 2 + 0) * 16 + l15;
    const int ia1 = M0g + (wv * 2 + 1) * 16 + l15;
    floatx4 accP[2][8];
    #pragma unroll
    for (int mt = 0; mt < 2; mt++)
        #pragma unroll
        for (int sl = 0; sl < 8; sl++) accP[mt][sl] = (floatx4){0.f, 0.f, 0.f, 0.f};
    {
        f16x8 aq[4][2];
        #define ALOADZ(S, KS) do { \
            aq[S][0] = ldzx8(z, x, ia0, (KS) * 32 + q2 * 8); \
            aq[S][1] = ldzx8(z, x, ia1, (KS) * 32 + q2 * 8); \
        } while (0)
        ALOADZ(0, 0); ALOADZ(1, 1); ALOADZ(2, 2);
        #pragma unroll
        for (int ks = 0; ks < 8; ks++) {
            if (ks < 5) { ALOADZ((ks + 3) & 3, ks + 3); }
            f16x8 a0 = aq[ks & 3][0];
            f16x8 a1 = aq[ks & 3][1];
            const uint32_t kadd = (uint32_t)((ks >> 2) << 8);
            const uint32_t kxor = (uint32_t)((ks & 3) << 6);
            #pragma unroll
            for (int sl = 0; sl < 8; sl++) {
                f16x8 b = *(const f16x8*)(smem + ((pb[sl] + kadd) ^ kxor));
                accP[0][sl] = __builtin_amdgcn_mfma_f32_16x16x32_f16(a0, b, accP[0][sl], 0, 0, 0);
                accP[1][sl] = __builtin_amdgcn_mfma_f32_16x16x32_f16(a1, b, accP[1][sl], 0, 0, 0);
            }
        }
        #undef ALOADZ
    }

    // ---- gi -> registers (+bias); h0 -> hstore ----
    float gi[2][3][2][4];
    #pragma unroll
    for (int mt = 0; mt < 2; mt++)
        #pragma unroll
        for (int g = 0; g < 3; g++)
            #pragma unroll
            for (int jt = 0; jt < 2; jt++)
                #pragma unroll
                for (int reg = 0; reg < 4; reg++)
                    gi[mt][g][jt][reg] = accP[mt][g * 2 + jt][reg] + bih[g][jt];
    #pragma unroll
    for (int mt = 0; mt < 2; mt++)
        #pragma unroll
        for (int jt = 0; jt < 2; jt++)
            #pragma unroll
            for (int reg = 0; reg < 4; reg++) {
                int rl = (wv * 2 + mt) * 16 + q2 * 4 + reg;
                float v = accP[mt][6 + jt][reg] + bh0[jt];
                *(_Float16*)(smem + HST + (uint32_t)(rl * 64 + (jt * 16 + l15) * 2)) = (_Float16)v;
            }
    __syncthreads();   // pre-B reads + hstore writes complete

    // ---- inline steady-B staging: 96 rows x 512 fp16 (1KB rows) from W_hh ----
    #pragma unroll
    for (int u = 0; u < 12; u++) {
        int sl2 = u * 512 + tid;            // 0..6143
        int r = sl2 >> 6, l = sl2 & 63;     // row 0..95, slot 0..63
        int nrow = (r >> 5) * 512 + jc0 + (r & 31);
        int c = (l ^ (r & 15)) << 3;
        const float4* src = (const float4*)(W_hh + (size_t)nrow * 512 + c);
        float4 a = src[0], b = src[1];
        f16x8 v = {(_Float16)a.x, (_Float16)a.y, (_Float16)a.z, (_Float16)a.w,
                   (_Float16)b.x, (_Float16)b.y, (_Float16)b.z, (_Float16)b.w};
        *(f16x8*)(smem + (uint32_t)(r * 1024 + l * 16)) = v;
    }
    // ---- publish h0 (block-major, contiguous own lines) ----
    {
        int row = tid >> 1, half = tid & 1;
        const char* sl = smem + HST + (uint32_t)(row * 64 + half * 32);
        char* gd = (char*)&g_h[0][0] + (size_t)gidx * 262144 + (size_t)cgrp * 16384 +
                   (size_t)row * 64 + (size_t)half * 32;
        *(f16x8*)gd = *(const f16x8*)sl;
        *(f16x8*)(gd + 16) = *(const f16x8*)(sl + 16);
    }
    group_barrier16(gidx);   // drains B ds_writes + h0 publish

    // ---- 12-step loop ----
    #pragma unroll 1
    for (int t = 0; t < 12; t++) {
        // prologue P-loads issued FIRST (deepest in queue, consumed after GEMM)
        float pv[16];
        if (t > 0) {
            const float* pbase = &g_P[t - 1][0] + (size_t)gidx * 8192 +
                                 (size_t)(wv * 32 + (lane >> 1)) * 2 + (size_t)(lane & 1);
            #pragma unroll
            for (int c = 0; c < 16; c++) pv[c] = pbase[c * 512];
        }

        // warm next-step publish regions (RFO prefetch, overlapped with GEMM)
        if (t < 11 && wv == 0) {
            const char* wb = (const char*)&g_h[t + 1][0] + (size_t)gidx * 262144 +
                             (size_t)cgrp * 16384 + (size_t)lane * 128;
            async16(smem + DUM, wb);
            async16(smem + DUM, wb + 8192);
        }
        if (wv == 1) {
            const char* wp = (const char*)&g_P[t][0] +
                             ((size_t)gidx * 8192 + (size_t)cgrp * 512) * 4 +
                             (size_t)(lane & 15) * 128;
            async16(smem + DUM, wp);
        }

        // GEMM: K=512, A from g_h[t] (block-major: ks slab = 16KB), depth-8 ring
        const char* hb = (const char*)&g_h[t][0] + (size_t)gidx * 262144 + (size_t)q2 * 16;
        const char* rp0 = hb + (size_t)((wv * 2 + 0) * 16 + l15) * 64;
        const char* rp1 = hb + (size_t)((wv * 2 + 1) * 16 + l15) * 64;
        floatx4 acc[2][3][2];
        #pragma unroll
        for (int mt = 0; mt < 2; mt++)
            #pragma unroll
            for (int g = 0; g < 3; g++)
                #pragma unroll
                for (int jt = 0; jt < 2; jt++)
                    acc[mt][g][jt] = (floatx4){0.f, 0.f, 0.f, 0.f};

        f16x8 aq[8][2];
        #define ALOAD(S, KS) do { \
            aq[S][0] = *(const f16x8*)(rp0 + (size_t)(KS) * 16384); \
            aq[S][1] = *(const f16x8*)(rp1 + (size_t)(KS) * 16384); \
        } while (0)
        ALOAD(0, 0); ALOAD(1, 1); ALOAD(2, 2); ALOAD(3, 3);
        ALOAD(4, 4); ALOAD(5, 5); ALOAD(6, 6); ALOAD(7, 7);

        #pragma unroll
        for (int ks = 0; ks < 16; ks++) {
            f16x8 a0 = aq[ks & 7][0];
            f16x8 a1 = aq[ks & 7][1];
            if (ks < 8) { ALOAD(ks & 7, ks + 8); }
            const uint32_t kadd = (uint32_t)((ks >> 2) << 8);
            const uint32_t kxor = (uint32_t)((ks & 3) << 6);
            #pragma unroll
            for (int g = 0; g < 3; g++)
                #pragma unroll
                for (int jt = 0; jt < 2; jt++) {
                    f16x8 b = *(const f16x8*)(smem + ((bbase[g * 2 + jt] + kadd) ^ kxor));
                    acc[0][g][jt] = __builtin_amdgcn_mfma_f32_16x16x32_f16(a0, b, acc[0][g][jt], 0, 0, 0);
                    acc[1][g][jt] = __builtin_amdgcn_mfma_f32_16x16x32_f16(a1, b, acc[1][g][jt], 0, 0, 0);
                }
        }
        #undef ALOAD

        // prologue finish (wave-private): x_t for wave's 32 rows
        {
            float v;
            if (t == 0) {
                int i = M0g + wv * 32 + (lane >> 1);
                float4 xr = *(const float4*)(x0 + (size_t)i * 4);
                v = bia_d + xr.x * wia_d.x + xr.y * wia_d.y +
                            xr.z * wia_d.z + xr.w * wia_d.w;
            } else {
                v = bo;
                #pragma unroll
                for (int c = 0; c < 16; c++) v += pv[c];
                douts[wv * 768 + (t - 1) * 64 + lane] = v;   // stash out_{t-1}
            }
            xs[wv * 64 + lane] = v;
        }

        // epilogue (wave-private rows): gates, hn -> hstore, reduce -> g_P[t]
        #pragma unroll
        for (int mt = 0; mt < 2; mt++) {
            float po[4][2];
            #pragma unroll
            for (int reg = 0; reg < 4; reg++) { po[reg][0] = 0.f; po[reg][1] = 0.f; }
            #pragma unroll
            for (int jt = 0; jt < 2; jt++) {
                #pragma unroll
                for (int reg = 0; reg < 4; reg++) {
                    int local = mt * 16 + q2 * 4 + reg;        // 0..31 in wave
                    int rl = wv * 32 + local;                  // 0..255 in block
                    float2 xv = *(const float2*)(smem + XSO + (uint32_t)((wv * 64 + local * 2) * 4));
                    _Float16* hp = (_Float16*)(smem + HST + (uint32_t)(rl * 64 + (jt * 16 + l15) * 2));
                    float hold = (float)hp[0];
                    float r  = sigm_f(gi[mt][0][jt][reg] + p0v[jt].x * xv.x + p0v[jt].y * xv.y + acc[mt][0][jt][reg] + p1v[jt].z);
                    float u  = sigm_f(gi[mt][1][jt][reg] + p0v[jt].z * xv.x + p0v[jt].w * xv.y + acc[mt][1][jt][reg] + p1v[jt].w);
                    float nn = tanh_f(gi[mt][2][jt][reg] + p1v[jt].x * xv.x + p1v[jt].y * xv.y + r * (acc[mt][2][jt][reg] + p2v[jt].x));
                    float hn = (1.f - u) * nn + u * hold;
                    hp[0] = (_Float16)hn;
                    po[reg][0] += hn * wo0[jt];
                    po[reg][1] += hn * wo1[jt];
                }
            }
            #pragma unroll
            for (int m = 1; m < 16; m <<= 1)
                #pragma unroll
                for (int reg = 0; reg < 4; reg++) {
                    po[reg][0] += __shfl_xor(po[reg][0], m);
                    po[reg][1] += __shfl_xor(po[reg][1], m);
                }
            if (l15 == 0) {
                #pragma unroll
                for (int reg = 0; reg < 4; reg++) {
                    int local = mt * 16 + q2 * 4 + reg;
                    float* pp = &g_P[t][0] + (size_t)gidx * 8192 + (size_t)cgrp * 512 +
                                (size_t)(wv * 32 + local) * 2;
                    *(float2*)pp = make_float2(po[reg][0], po[reg][1]);
                }
            }
        }

        // publish h (wave-private 2KB slice, block-major contiguous)
        if (t < 11) {
            int rloc = wv * 32 + (lane >> 1);
            int half = lane & 1;
            const char* sl = smem + HST + (uint32_t)(rloc * 64 + half * 32);
            char* gd = (char*)&g_h[t + 1][0] + (size_t)gidx * 262144 +
                       (size_t)cgrp * 16384 + (size_t)rloc * 64 + (size_t)half * 32;
            *(f16x8*)gd = *(const f16x8*)sl;
            *(f16x8*)(gd + 16) = *(const f16x8*)(sl + 16);
        }
        group_barrier16(gidx);
    }

    // ---- final: out_11 + dout flush (cgrp 0 blocks only) ----
    if (cgrp == 0) {
        const float* pbase = &g_P[11][0] + (size_t)gidx * 8192 +
                             (size_t)(wv * 32 + (lane >> 1)) * 2 + (size_t)(lane & 1);
        float v = bo;
        #pragma unroll
        for (int c = 0; c < 16; c++) v += pbase[c * 512];
        douts[wv * 768 + 11 * 64 + lane] = v;
        size_t i = (size_t)(M0g + wv * 32 + (lane >> 1));
        int d = lane & 1;
        #pragma unroll
        for (int t = 0; t < 12; t++)
            dout[(i * 12 + t) * 2 + d] = douts[wv * 768 + t * 64 + lane];
    }
}

extern "C" void kernel_launch(void* const* d_in, const int* in_sizes, int n_in,
                              void* d_out, int out_size, void* d_ws, size_t ws_size,
                              hipStream_t stream)
{
    const float* z     = (const float*)d_in[0];
    const float* x     = (const float*)d_in[1];
    const float* x0    = (const float*)d_in[2];
    const float* W_ia  = (const float*)d_in[3];
    const float* b_ia  = (const float*)d_in[4];
    const float* W_h0  = (const float*)d_in[5];
    const float* b_h0  = (const float*)d_in[6];
    const float* W_ih  = (const float*)d_in[7];
    const float* b_ih  = (const float*)d_in[8];
    const float* W_hh  = (const float*)d_in[9];
    const float* b_hh  = (const float*)d_in[10];
    const float* W_out = (const float*)d_in[11];
    const float* b_out = (const float*)d_in[12];
    float* dout = (float*)d_out;

    static bool s_attr_done = false;
    if (!s_attr_done) {
        hipFuncSetAttribute((const void*)k_all,
                            hipFuncAttributeMaxDynamicSharedMemorySize, 142400);
        s_attr_done = true;
    }

    k_all<<<256, 512, 142400, stream>>>(z, x, x0, W_ia, b_ia, W_h0, b_h0,
                                        W_ih, b_ih, W_hh, b_hh, W_out, b_out,
                                        dout);
}

// Round 16
// 225.466 us; speedup vs baseline: 1.2169x; 1.2169x over previous
//
#include <hip/hip_runtime.h>
#include <cstdint>
#include <cstddef>

// R21: R19 champion + L2-RESIDENT PING-PONG exchange. The 12 step-indexed
// fresh h/P buffers (48+12MB: first-touch RFO + dirty evictions dominated
// FETCH/WRITE and the RFO wait sat in the barrier's vmcnt(0) drain) are
// replaced by 2 ping-pong buffers (8+2MB, permanently L2-resident per XCD).
// Fresh buffers existed only to keep plain consumer loads L1-safe; consumers
// now use `sc0` loads (inline asm: bypass per-CU L1, hit the XCD-coherent
// L2) with a hand-counted vmcnt ring (never drained mid-loop; N =
// 20,20,20,4x11,2,0; 16 P-loads stay in flight under the whole GEMM) +
// sched_barrier(0) after each wait (rule #18). Producers keep plain
// write-through stores + barrier vmcnt(0) drain (validated R11-R19).
// In-loop warming deleted (lines stay L2-resident). Everything else verbatim.

typedef __attribute__((ext_vector_type(8))) _Float16 f16x8;
typedef __attribute__((ext_vector_type(4))) float floatx4;

__device__ unsigned g_cnt[8 * 64];     // per-XCD registration tickets
__device__ unsigned g_gbar[16 * 64];   // per-group barrier counters (padded)

// Ping-pong exchange buffers (L2-resident per XCD):
// g_h2[b]: [16 grp][16 cgrp][256 rows][32 cols] fp16 (cgrp slab = 16KB).
// g_P2[b]: [16 grp][16 cgrp][512] f32 (block slab = 2KB).
__device__ __align__(256) _Float16 g_h2[2][16 * 16 * 256 * 32];
__device__ __align__(256) float    g_P2[2][16 * 16 * 512];

__device__ __forceinline__ float sigm_f(float v) { return 1.0f / (1.0f + __expf(-v)); }
__device__ __forceinline__ float tanh_f(float v) { return 2.0f / (1.0f + __expf(-2.0f * v)) - 1.0f; }

__device__ __forceinline__ void async16(void* lds, const void* g) {
    __builtin_amdgcn_global_load_lds(
        (const __attribute__((address_space(1))) void*)g,
        (__attribute__((address_space(3))) void*)lds, 16, 0, 0);
}

// sc0 loads: bypass per-CU L1, served by the XCD-coherent L2. Results are
// NOT ready at the asm statement -- callers enforce hand-counted s_waitcnt
// vmcnt(N) + sched_barrier(0) before first use.
__device__ __forceinline__ void aload16(f16x8& d, const char* p) {
    asm volatile("global_load_dwordx4 %0, %1, off sc0" : "=&v"(d) : "v"(p));
}
__device__ __forceinline__ void pload4(float& d, const float* p) {
    asm volatile("global_load_dword %0, %1, off sc0" : "=&v"(d) : "v"(p));
}

// Per-group barrier: EXACTLY 16 co-resident same-XCD blocks (validated R11-R19).
__device__ __forceinline__ void group_barrier16(unsigned gidx) {
    asm volatile("s_waitcnt vmcnt(0)" ::: "memory");
    __syncthreads();
    if (threadIdx.x == 0) {
        unsigned* ctr = &g_gbar[gidx * 64];
        unsigned t = __hip_atomic_fetch_add(ctr, 1u, __ATOMIC_RELAXED,
                                            __HIP_MEMORY_SCOPE_AGENT);
        unsigned target = (t & ~15u) + 16u;
        while (__hip_atomic_load(ctr, __ATOMIC_RELAXED,
                                 __HIP_MEMORY_SCOPE_AGENT) < target)
            __builtin_amdgcn_s_sleep(1);
    }
    __syncthreads();
}

// Load 8 cols of the virtual zx row i (cols 0..127 = z, 128..255 = x) as fp16.
__device__ __forceinline__ f16x8 ldzx8(const float* __restrict__ z,
                                       const float* __restrict__ x,
                                       int i, int c) {
    const float* s = (c < 128) ? (z + (size_t)i * 128 + c)
                               : (x + (size_t)i * 128 + (c - 128));
    float4 a = ((const float4*)s)[0], b = ((const float4*)s)[1];
    return (f16x8){(_Float16)a.x, (_Float16)a.y, (_Float16)a.z, (_Float16)a.w,
                   (_Float16)b.x, (_Float16)b.y, (_Float16)b.z, (_Float16)b.w};
}

// ---------------- K: fully fused (prep + pre-GEMM + 12-step GRU) ----------------
// LDS: B @0 (96KB steady; 64KB pre-phase overlap), hstore[256][32]h @98304
// (16KB), xs[8][64]f @114688 (2KB), douts[8][12][64]f @116736 (24KB),
// dummy @141312 (1KB), slot @142336. Request 142400 (>80KB => 1 blk/CU).
__global__ __launch_bounds__(512, 1) void k_all(
    const float* __restrict__ z, const float* __restrict__ x,
    const float* __restrict__ x0, const float* __restrict__ W_ia,
    const float* __restrict__ b_ia, const float* __restrict__ W_h0,
    const float* __restrict__ b_h0, const float* __restrict__ W_ih,
    const float* __restrict__ b_ih, const float* __restrict__ W_hh,
    const float* __restrict__ b_hh, const float* __restrict__ W_out,
    const float* __restrict__ b_out, float* __restrict__ dout)
{
    extern __shared__ __align__(16) char smem[];
    const uint32_t BOFF = 0, HST = 98304, XSO = 114688, DOUT = 116736,
                   DUM = 141312, SLO = 142336;
    const int tid = threadIdx.x;
    float* xs = (float*)(smem + XSO);
    float* douts = (float*)(smem + DOUT);

    // ---- XCD discovery + registration (1 blk/CU => exactly 32 blks/XCD) ----
    unsigned xcc;
    asm volatile("s_getreg_b32 %0, hwreg(HW_REG_XCC_ID)" : "=s"(xcc));
    xcc &= 7u;
    if (tid == 0) {
        unsigned s = __hip_atomic_fetch_add(&g_cnt[xcc * 64], 1u, __ATOMIC_RELAXED,
                                            __HIP_MEMORY_SCOPE_AGENT) & 31u;
        *(unsigned*)(smem + SLO) = s;
    }
    __syncthreads();
    const unsigned slot = *(volatile unsigned*)(smem + SLO);
    const int shalf = slot >> 4, cgrp = slot & 15;
    const unsigned gidx = xcc * 2 + shalf;      // 0..15, 16 blocks each
    const int M0g = (int)gidx * 256;            // group's global sample base
    const int jc0 = cgrp * 32;                  // block's 32 h-cols (x3 gates)

    const int wv = tid >> 6, lane = tid & 63;
    const int l15 = lane & 15, q2 = lane >> 4;

    // ---- one-time warm of BOTH ping-pong slabs (RFO prefetch) ----
    if (wv == 0) {
        const char* wb = (const char*)&g_h2[0][0] + (size_t)gidx * 262144 +
                         (size_t)cgrp * 16384 + (size_t)lane * 128;
        async16(smem + DUM, wb);
        async16(smem + DUM, wb + 8192);
    }
    if (wv == 1) {
        const char* wb = (const char*)&g_h2[1][0] + (size_t)gidx * 262144 +
                         (size_t)cgrp * 16384 + (size_t)lane * 128;
        async16(smem + DUM, wb);
        async16(smem + DUM, wb + 8192);
    }
    if (wv == 2) {
        const char* wp = (const char*)&g_P2[0][0] +
                         ((size_t)gidx * 8192 + (size_t)cgrp * 512) * 4 +
                         (size_t)(lane & 15) * 128;
        async16(smem + DUM, wp);
    }
    if (wv == 3) {
        const char* wp = (const char*)&g_P2[1][0] +
                         ((size_t)gidx * 8192 + (size_t)cgrp * 512) * 4 +
                         (size_t)(lane & 15) * 128;
        async16(smem + DUM, wp);
    }

    // ---- inline pre-B staging: 128 rows x 256 fp16 (512B rows) from f32 ----
    #pragma unroll
    for (int u = 0; u < 8; u++) {
        int sl2 = u * 512 + tid;            // 0..4095
        int r = sl2 >> 5, s = sl2 & 31;     // row 0..127, slot 0..31
        int c = (s ^ (r & 15)) << 3;        // col base, multiple of 8
        f16x8 v;
        if (r < 96) {
            int nrow = (r >> 5) * 512 + jc0 + (r & 31);     // W_ih row
            const float2* src = (const float2*)(W_ih + (size_t)nrow * 258 + c);
            float2 a0 = src[0], a1 = src[1], a2 = src[2], a3 = src[3];
            v = (f16x8){(_Float16)a0.x, (_Float16)a0.y, (_Float16)a1.x, (_Float16)a1.y,
                        (_Float16)a2.x, (_Float16)a2.y, (_Float16)a3.x, (_Float16)a3.y};
        } else {
            int nrow = jc0 + (r - 96);                      // W_h0 row
            const float4* src = (const float4*)(W_h0 + (size_t)nrow * 256 + c);
            float4 a = src[0], b = src[1];
            v = (f16x8){(_Float16)a.x, (_Float16)a.y, (_Float16)a.z, (_Float16)a.w,
                        (_Float16)b.x, (_Float16)b.y, (_Float16)b.z, (_Float16)b.w};
        }
        *(f16x8*)(smem + (uint32_t)(r * 512 + s * 16)) = v;
    }

    // ---- t-invariant params: direct f32 scalar loads ----
    float4 p0v[2], p1v[2], p2v[2]; float wo0[2], wo1[2];
    float bih[3][2], bh0[2];
    #pragma unroll
    for (int jt = 0; jt < 2; jt++) {
        int jc = jc0 + jt * 16 + l15;
        p0v[jt] = make_float4(W_ih[(size_t)jc * 258 + 256],
                              W_ih[(size_t)jc * 258 + 257],
                              W_ih[(size_t)(512 + jc) * 258 + 256],
                              W_ih[(size_t)(512 + jc) * 258 + 257]);
        p1v[jt] = make_float4(W_ih[(size_t)(1024 + jc) * 258 + 256],
                              W_ih[(size_t)(1024 + jc) * 258 + 257],
                              b_hh[jc], b_hh[512 + jc]);
        p2v[jt] = make_float4(b_hh[1024 + jc], W_out[jc], W_out[512 + jc], 0.f);
        wo0[jt] = p2v[jt].y; wo1[jt] = p2v[jt].z;
        bh0[jt] = b_h0[jc];
        #pragma unroll
        for (int g = 0; g < 3; g++) bih[g][jt] = b_ih[g * 512 + jc];
    }
    const float bo = b_out[lane & 1];
    const float bia_d = b_ia[lane & 1];
    float4 wia_d = make_float4(W_ia[(lane & 1) * 4 + 0], W_ia[(lane & 1) * 4 + 1],
                               W_ia[(lane & 1) * 4 + 2], W_ia[(lane & 1) * 4 + 3]);

    uint32_t bbase[6];   // steady B (96 rows x 1024B) [validated swizzle]
    #pragma unroll
    for (int g = 0; g < 3; g++)
        #pragma unroll
        for (int jt = 0; jt < 2; jt++) {
            int r = g * 32 + jt * 16 + l15;
            bbase[g * 2 + jt] = BOFF + (uint32_t)r * 1024 +
                                ((uint32_t)(q2 ^ (r & 3)) << 4) +
                                ((uint32_t)((r >> 2) & 3) << 6);
        }
    uint32_t pb[8];      // pre-B (128 rows x 512B): 0..5 gates, 6..7 h0
    #pragma unroll
    for (int sl = 0; sl < 8; sl++) {
        int r = (sl < 6) ? ((sl >> 1) * 32 + (sl & 1) * 16 + l15)
                         : (96 + (sl - 6) * 16 + l15);
        pb[sl] = BOFF + (uint32_t)r * 512 +
                 ((uint32_t)(q2 ^ (r & 3)) << 4) +
                 ((uint32_t)((r >> 2) & 3) << 6);
    }
    __syncthreads();   // pre-B staged (ds_writes drained by barrier)

    // ---- pre-GEMM: K=256, A from z/x f32 (cvt in-register), 8 ks ----
    const int ia0 = M0g + (wv * 2 + 0) * 16 + l15;
    const int ia1 = M0g + (wv * 2 + 1) * 16 + l15;
    floatx4 accP[2][8];
    #pragma unroll
    for (int mt = 0; mt < 2; mt++)
        #pragma unroll
        for (int sl = 0; sl < 8; sl++) accP[mt][sl] = (floatx4){0.f, 0.f, 0.f, 0.f};
    {
        f16x8 aqz[4][2];
        #define ALOADZ(S, KS) do { \
            aqz[S][0] = ldzx8(z, x, ia0, (KS) * 32 + q2 * 8); \
            aqz[S][1] = ldzx8(z, x, ia1, (KS) * 32 + q2 * 8); \
        } while (0)
        ALOADZ(0, 0); ALOADZ(1, 1); ALOADZ(2, 2);
        #pragma unroll
        for (int ks = 0; ks < 8; ks++) {
            if (ks < 5) { ALOADZ((ks + 3) & 3, ks + 3); }
            f16x8 a0 = aqz[ks & 3][0];
            f16x8 a1 = aqz[ks & 3][1];
            const uint32_t kadd = (uint32_t)((ks >> 2) << 8);
            const uint32_t kxor = (uint32_t)((ks & 3) << 6);
            #pragma unroll
            for (int sl = 0; sl < 8; sl++) {
                f16x8 b = *(const f16x8*)(smem + ((pb[sl] + kadd) ^ kxor));
                accP[0][sl] = __builtin_amdgcn_mfma_f32_16x16x32_f16(a0, b, accP[0][sl], 0, 0, 0);
                accP[1][sl] = __builtin_amdgcn_mfma_f32_16x16x32_f16(a1, b, accP[1][sl], 0, 0, 0);
            }
        }
        #undef ALOADZ
    }

    // ---- gi -> registers (+bias); h0 -> hstore ----
    float gi[2][3][2][4];
    #pragma unroll
    for (int mt = 0; mt < 2; mt++)
        #pragma unroll
        for (int g = 0; g < 3; g++)
            #pragma unroll
            for (int jt = 0; jt < 2; jt++)
                #pragma unroll
                for (int reg = 0; reg < 4; reg++)
                    gi[mt][g][jt][reg] = accP[mt][g * 2 + jt][reg] + bih[g][jt];
    #pragma unroll
    for (int mt = 0; mt < 2; mt++)
        #pragma unroll
        for (int jt = 0; jt < 2; jt++)
            #pragma unroll
            for (int reg = 0; reg < 4; reg++) {
                int rl = (wv * 2 + mt) * 16 + q2 * 4 + reg;
                float v = accP[mt][6 + jt][reg] + bh0[jt];
                *(_Float16*)(smem + HST + (uint32_t)(rl * 64 + (jt * 16 + l15) * 2)) = (_Float16)v;
            }
    __syncthreads();   // pre-B reads + hstore writes complete

    // ---- inline steady-B staging: 96 rows x 512 fp16 (1KB rows) from W_hh ----
    #pragma unroll
    for (int u = 0; u < 12; u++) {
        int sl2 = u * 512 + tid;            // 0..6143
        int r = sl2 >> 6, l = sl2 & 63;     // row 0..95, slot 0..63
        int nrow = (r >> 5) * 512 + jc0 + (r & 31);
        int c = (l ^ (r & 15)) << 3;
        const float4* src = (const float4*)(W_hh + (size_t)nrow * 512 + c);
        float4 a = src[0], b = src[1];
        f16x8 v = {(_Float16)a.x, (_Float16)a.y, (_Float16)a.z, (_Float16)a.w,
                   (_Float16)b.x, (_Float16)b.y, (_Float16)b.z, (_Float16)b.w};
        *(f16x8*)(smem + (uint32_t)(r * 1024 + l * 16)) = v;
    }
    // ---- publish h0 into g_h2[0] (block-major, contiguous own lines) ----
    {
        int row = tid >> 1, half = tid & 1;
        const char* sl = smem + HST + (uint32_t)(row * 64 + half * 32);
        char* gd = (char*)&g_h2[0][0] + (size_t)gidx * 262144 + (size_t)cgrp * 16384 +
                   (size_t)row * 64 + (size_t)half * 32;
        *(f16x8*)gd = *(const f16x8*)sl;
        *(f16x8*)(gd + 16) = *(const f16x8*)(sl + 16);
    }
    group_barrier16(gidx);   // drains B ds_writes + h0 publish + warming

    // ---- 12-step loop ----
    #pragma unroll 1
    for (int t = 0; t < 12; t++) {
        // t==0 prologue fully BEFORE the asm-load window (keeps vmcnt clean-ish)
        if (t == 0) {
            int i = M0g + wv * 32 + (lane >> 1);
            float4 xr = *(const float4*)(x0 + (size_t)i * 4);
            float v = bia_d + xr.x * wia_d.x + xr.y * wia_d.y +
                      xr.z * wia_d.z + xr.w * wia_d.w;
            xs[wv * 64 + lane] = v;
        }

        // GEMM: K=512, A from g_h2[t&1] via sc0 (bypass L1, hit L2).
        // Issue order: A slots 0..2 (6 loads), then 16 P loads (stay in
        // flight under the whole GEMM), then ring issues. Hand-counted
        // vmcnt: N = 20 (ks<3), 4 (3<=ks<14), 2 (ks=14), 0 (ks=15).
        const char* hb = (const char*)&g_h2[t & 1][0] + (size_t)gidx * 262144 +
                         (size_t)q2 * 16;
        const char* rp0 = hb + (size_t)((wv * 2 + 0) * 16 + l15) * 64;
        const char* rp1 = hb + (size_t)((wv * 2 + 1) * 16 + l15) * 64;
        floatx4 acc[2][3][2];
        #pragma unroll
        for (int mt = 0; mt < 2; mt++)
            #pragma unroll
            for (int g = 0; g < 3; g++)
                #pragma unroll
                for (int jt = 0; jt < 2; jt++)
                    acc[mt][g][jt] = (floatx4){0.f, 0.f, 0.f, 0.f};

        f16x8 aq[4][2];
        #define AISS(S, KS) do { \
            aload16(aq[S][0], rp0 + (size_t)(KS) * 16384); \
            aload16(aq[S][1], rp1 + (size_t)(KS) * 16384); \
        } while (0)
        AISS(0, 0); AISS(1, 1); AISS(2, 2);

        float pv[16];
        {   // P loads (sc0): read g_P2[(t+1)&1] (garbage at t=0, unused)
            const float* pbase = &g_P2[(t + 1) & 1][0] + (size_t)gidx * 8192 +
                                 (size_t)(wv * 32 + (lane >> 1)) * 2 + (size_t)(lane & 1);
            #pragma unroll
            for (int c = 0; c < 16; c++) pload4(pv[c], pbase + c * 512);
        }

        #pragma unroll
        for (int ks = 0; ks < 16; ks++) {
            if (ks < 3)        asm volatile("s_waitcnt vmcnt(20)" ::: "memory");
            else if (ks < 14)  asm volatile("s_waitcnt vmcnt(4)"  ::: "memory");
            else if (ks == 14) asm volatile("s_waitcnt vmcnt(2)"  ::: "memory");
            else               asm volatile("s_waitcnt vmcnt(0)"  ::: "memory");
            __builtin_amdgcn_sched_barrier(0);
            f16x8 a0 = aq[ks & 3][0];
            f16x8 a1 = aq[ks & 3][1];
            if (ks < 13) { AISS((ks + 3) & 3, ks + 3); }
            const uint32_t kadd = (uint32_t)((ks >> 2) << 8);
            const uint32_t kxor = (uint32_t)((ks & 3) << 6);
            #pragma unroll
            for (int g = 0; g < 3; g++)
                #pragma unroll
                for (int jt = 0; jt < 2; jt++) {
                    f16x8 b = *(const f16x8*)(smem + ((bbase[g * 2 + jt] + kadd) ^ kxor));
                    acc[0][g][jt] = __builtin_amdgcn_mfma_f32_16x16x32_f16(a0, b, acc[0][g][jt], 0, 0, 0);
                    acc[1][g][jt] = __builtin_amdgcn_mfma_f32_16x16x32_f16(a1, b, acc[1][g][jt], 0, 0, 0);
                }
        }
        #undef AISS

        // prologue finish (wave-private): x_t for wave's 32 rows (pv drained)
        if (t > 0) {
            float v = bo;
            #pragma unroll
            for (int c = 0; c < 16; c++) v += pv[c];
            douts[wv * 768 + (t - 1) * 64 + lane] = v;   // stash out_{t-1}
            xs[wv * 64 + lane] = v;
        }

        // epilogue (wave-private rows): gates, hn -> hstore, reduce -> g_P2[t&1]
        #pragma unroll
        for (int mt = 0; mt < 2; mt++) {
            float po[4][2];
            #pragma unroll
            for (int reg = 0; reg < 4; reg++) { po[reg][0] = 0.f; po[reg][1] = 0.f; }
            #pragma unroll
            for (int jt = 0; jt < 2; jt++) {
                #pragma unroll
                for (int reg = 0; reg < 4; reg++) {
                    int local = mt * 16 + q2 * 4 + reg;        // 0..31 in wave
                    int rl = wv * 32 + local;                  // 0..255 in block
                    float2 xv = *(const float2*)(smem + XSO + (uint32_t)((wv * 64 + local * 2) * 4));
                    _Float16* hp = (_Float16*)(smem + HST + (uint32_t)(rl * 64 + (jt * 16 + l15) * 2));
                    float hold = (float)hp[0];
                    float r  = sigm_f(gi[mt][0][jt][reg] + p0v[jt].x * xv.x + p0v[jt].y * xv.y + acc[mt][0][jt][reg] + p1v[jt].z);
                    float u  = sigm_f(gi[mt][1][jt][reg] + p0v[jt].z * xv.x + p0v[jt].w * xv.y + acc[mt][1][jt][reg] + p1v[jt].w);
                    float nn = tanh_f(gi[mt][2][jt][reg] + p1v[jt].x * xv.x + p1v[jt].y * xv.y + r * (acc[mt][2][jt][reg] + p2v[jt].x));
                    float hn = (1.f - u) * nn + u * hold;
                    hp[0] = (_Float16)hn;
                    po[reg][0] += hn * wo0[jt];
                    po[reg][1] += hn * wo1[jt];
                }
            }
            #pragma unroll
            for (int m = 1; m < 16; m <<= 1)
                #pragma unroll
                for (int reg = 0; reg < 4; reg++) {
                    po[reg][0] += __shfl_xor(po[reg][0], m);
                    po[reg][1] += __shfl_xor(po[reg][1], m);
                }
            if (l15 == 0) {
                #pragma unroll
                for (int reg = 0; reg < 4; reg++) {
                    int local = mt * 16 + q2 * 4 + reg;
                    float* pp = &g_P2[t & 1][0] + (size_t)gidx * 8192 + (size_t)cgrp * 512 +
                                (size_t)(wv * 32 + local) * 2;
                    *(float2*)pp = make_float2(po[reg][0], po[reg][1]);
                }
            }
        }

        // publish h -> g_h2[(t+1)&1] (wave-private 2KB slice, block-contiguous)
        if (t < 11) {
            int rloc = wv * 32 + (lane >> 1);
            int half = lane & 1;
            const char* sl = smem + HST + (uint32_t)(rloc * 64 + half * 32);
            char* gd = (char*)&g_h2[(t + 1) & 1][0] + (size_t)gidx * 262144 +
                       (size_t)cgrp * 16384 + (size_t)rloc * 64 + (size_t)half * 32;
            *(f16x8*)gd = *(const f16x8*)sl;
            *(f16x8*)(gd + 16) = *(const f16x8*)(sl + 16);
        }
        group_barrier16(gidx);
    }

    // ---- final: out_11 from g_P2[1] (sc0) + dout flush (cgrp 0 only) ----
    if (cgrp == 0) {
        float pv[16];
        const float* pbase = &g_P2[1][0] + (size_t)gidx * 8192 +
                             (size_t)(wv * 32 + (lane >> 1)) * 2 + (size_t)(lane & 1);
        #pragma unroll
        for (int c = 0; c < 16; c++) pload4(pv[c], pbase + c * 512);
        asm volatile("s_waitcnt vmcnt(0)" ::: "memory");
        __builtin_amdgcn_sched_barrier(0);
        float v = bo;
        #pragma unroll
        for (int c = 0; c < 16; c++) v += pv[c];
        douts[wv * 768 + 11 * 64 + lane] = v;
        size_t i = (size_t)(M0g + wv * 32 + (lane >> 1));
        int d = lane & 1;
        #pragma unroll
        for (int t = 0; t < 12; t++)
            dout[(i * 12 + t) * 2 + d] = douts[wv * 768 + t * 64 + lane];
    }
}

extern "C" void kernel_launch(void* const* d_in, const int* in_sizes, int n_in,
                              void* d_out, int out_size, void* d_ws, size_t ws_size,
                              hipStream_t stream)
{
    const float* z     = (const float*)d_in[0];
    const float* x     = (const float*)d_in[1];
    const float* x0    = (const float*)d_in[2];
    const float* W_ia  = (const float*)d_in[3];
    const float* b_ia  = (const float*)d_in[4];
    const float* W_h0  = (const float*)d_in[5];
    const float* b_h0  = (const float*)d_in[6];
    const float* W_ih  = (const float*)d_in[7];
    const float* b_ih  = (const float*)d_in[8];
    const float* W_hh  = (const float*)d_in[9];
    const float* b_hh  = (const float*)d_in[10];
    const float* W_out = (const float*)d_in[11];
    const float* b_out = (const float*)d_in[12];
    float* dout = (float*)d_out;

    static bool s_attr_done = false;
    if (!s_attr_done) {
        hipFuncSetAttribute((const void*)k_all,
                            hipFuncAttributeMaxDynamicSharedMemorySize, 142400);
        s_attr_done = true;
    }

    k_all<<<256, 512, 142400, stream>>>(z, x, x0, W_ia, b_ia, W_h0, b_h0,
                                        W_ih, b_ih, W_hh, b_hh, W_out, b_out,
                                        dout);
}